// Round 11
// baseline (275.639 us; speedup 1.0000x reference)
//
#include <hip/hip_runtime.h>

#define DIM 128
#define NSL 128            // edge slices per metapath (256 blocks total, 1/CU)
#define WMAX 25000         // N/4 packed-byte words (100 KB LDS, full N)

typedef __attribute__((ext_vector_type(8))) short bf16x8;
typedef __attribute__((ext_vector_type(4))) float f32x4;
typedef __attribute__((ext_vector_type(2))) float f32x2;

__device__ __forceinline__ unsigned bfbits(float f) {
    unsigned u = __float_as_uint(f);
    return (u + 0x7FFFu + ((u >> 16) & 1u)) >> 16;   // RNE bf16
}
__device__ __forceinline__ float bflo(unsigned u) { return __uint_as_float(u << 16); }
__device__ __forceinline__ float bfhi(unsigned u) { return __uint_as_float(u & 0xFFFF0000u); }

// ---- K1: h2(bf16) = x @ W_lin^T + b_lin via MFMA; fused al/beta epilogue ----
__global__ __launch_bounds__(256) void k_gemm_h(
    const float* __restrict__ x, const float* __restrict__ W,
    const float* __restrict__ b, const float* __restrict__ Wc,
    const float* __restrict__ bcv, const float* __restrict__ alw,
    const float* __restrict__ alb, const float* __restrict__ alpha,
    unsigned short* __restrict__ h2u, float* __restrict__ exal0,
    float* __restrict__ exal1, float* __restrict__ betab, int n)
{
    __shared__ short wlds[128 * 136];
    __shared__ short xlds[64 * 136];
    const int tid  = threadIdx.x;
    const int row0 = blockIdx.x * 64;

    {
        const int j = tid >> 1, half = tid & 1;
        const float4* W4 = (const float4*)W;
#pragma unroll
        for (int i = 0; i < 8; ++i) {
            float4 fa = W4[j * 32 + half * 16 + i * 2];
            float4 fb = W4[j * 32 + half * 16 + i * 2 + 1];
            uint4 p;
            p.x = bfbits(fa.x) | (bfbits(fa.y) << 16);
            p.y = bfbits(fa.z) | (bfbits(fa.w) << 16);
            p.z = bfbits(fb.x) | (bfbits(fb.y) << 16);
            p.w = bfbits(fb.z) | (bfbits(fb.w) << 16);
            *(uint4*)&wlds[j * 136 + half * 64 + i * 8] = p;
        }
    }
    {
        const int r = tid >> 2, q = tid & 3;
        const int row = min(row0 + r, n - 1);
        const float4* x4 = (const float4*)x;
#pragma unroll
        for (int i = 0; i < 4; ++i) {
            float4 fa = x4[(size_t)row * 32 + q * 8 + i * 2];
            float4 fb = x4[(size_t)row * 32 + q * 8 + i * 2 + 1];
            uint4 p;
            p.x = bfbits(fa.x) | (bfbits(fa.y) << 16);
            p.y = bfbits(fa.z) | (bfbits(fa.w) << 16);
            p.z = bfbits(fb.x) | (bfbits(fb.y) << 16);
            p.w = bfbits(fb.z) | (bfbits(fb.w) << 16);
            *(uint4*)&xlds[r * 136 + q * 32 + i * 8] = p;
        }
    }
    __syncthreads();

    const int wv = tid >> 6, lane = tid & 63;
    const int lr = lane & 15, lg = lane >> 4;

    f32x4 acc[8];
#pragma unroll
    for (int c = 0; c < 8; ++c) acc[c] = (f32x4){0.f, 0.f, 0.f, 0.f};

#pragma unroll
    for (int ks = 0; ks < 4; ++ks) {
        bf16x8 a = *(const bf16x8*)&xlds[(wv * 16 + lr) * 136 + ks * 32 + lg * 8];
#pragma unroll
        for (int c = 0; c < 8; ++c) {
            bf16x8 bb = *(const bf16x8*)&wlds[(c * 16 + lr) * 136 + ks * 32 + lg * 8];
            acc[c] = __builtin_amdgcn_mfma_f32_16x16x32_bf16(a, bb, acc[c], 0, 0, 0);
        }
    }

    // epilogue: C/D layout col=lane&15, row=(lane>>4)*4+reg  [m89-verified]
    const int rl0 = wv * 16 + lg * 4;      // local row base
    float as0[4] = {0.f,0.f,0.f,0.f}, as1[4] = {0.f,0.f,0.f,0.f};
#pragma unroll
    for (int c = 0; c < 8; ++c) {
        const int col = c * 16 + lr;
        const float bc = b[col];
        const float w0 = alw[col], w1 = alw[128 + col];
#pragma unroll
        for (int r = 0; r < 4; ++r) {
            const float hv = acc[c][r] + bc;
            const int row = row0 + rl0 + r;
            if (row < n)
                h2u[(size_t)row * DIM + col] = (unsigned short)bfbits(hv);
            as0[r] = fmaf(hv, w0, as0[r]);
            as1[r] = fmaf(hv, w1, as1[r]);
        }
    }
    float xs0[4] = {0.f,0.f,0.f,0.f}, xs1[4] = {0.f,0.f,0.f,0.f},
          xs2[4] = {0.f,0.f,0.f,0.f};
#pragma unroll
    for (int i = 0; i < 8; ++i) {
        const int col = lr + i * 16;
        const float wc0 = Wc[col], wc1 = Wc[128 + col], wc2 = Wc[256 + col];
#pragma unroll
        for (int r = 0; r < 4; ++r) {
            const float xv = bflo((unsigned)(unsigned short)xlds[(rl0 + r) * 136 + col]);
            xs0[r] = fmaf(xv, wc0, xs0[r]);
            xs1[r] = fmaf(xv, wc1, xs1[r]);
            xs2[r] = fmaf(xv, wc2, xs2[r]);
        }
    }
#pragma unroll
    for (int o = 1; o <= 8; o <<= 1) {
#pragma unroll
        for (int r = 0; r < 4; ++r) {
            as0[r] += __shfl_xor(as0[r], o);
            as1[r] += __shfl_xor(as1[r], o);
            xs0[r] += __shfl_xor(xs0[r], o);
            xs1[r] += __shfl_xor(xs1[r], o);
            xs2[r] += __shfl_xor(xs2[r], o);
        }
    }
    if (lr == 0) {
        const float a0 = alpha[0], a1 = alpha[1];
        const float ab0 = alb[0], ab1 = alb[1];
        const float b0 = bcv[0], b1 = bcv[1], b2 = bcv[2];
#pragma unroll
        for (int r = 0; r < 4; ++r) {
            const int row = row0 + rl0 + r;
            if (row < n) {
                exal0[row] = __expf(a0 * (as0[r] + ab0));
                exal1[row] = __expf(a1 * (as1[r] + ab1));
                float c0 = xs0[r] + b0, c1 = xs1[r] + b1, c2 = xs2[r] + b2;
                float mx = fmaxf(c0, fmaxf(c1, c2));
                float e0 = __expf(c0 - mx), e1 = __expf(c1 - mx),
                      e2 = __expf(c2 - mx);
                float s = e0 + e1 + e2;
                betab[row * 3 + 0] = e0 / s;
                betab[row * 3 + 1] = e1 / s;
                betab[row * 3 + 2] = e2 / s;
            }
        }
    }
}

// ---------------- K3: per-(metapath,slice) full-N LDS histogram ----------------
__global__ __launch_bounds__(1024) void k_hist(
    const int* __restrict__ ei1, const int* __restrict__ ei2,
    unsigned* __restrict__ pb, int n, int e)
{
    __shared__ unsigned lds[WMAX];
    const int blk = blockIdx.x;
    const int s   = blk % NSL;
    const int m   = blk / NSL;
    const int* ei = m ? ei2 : ei1;
    const int W   = (n + 3) >> 2;

    for (int i = threadIdx.x; i < W; i += 1024) lds[i] = 0;
    __syncthreads();

    const int sl = (e + NSL - 1) / NSL;
    const int j0 = s * sl, j1 = min(j0 + sl, e);
    for (int j = j0 + threadIdx.x; j < j1; j += 1024) {
        int d = ei[j];
        atomicAdd(&lds[d >> 2], 1u << ((d & 3) * 8));
    }
    __syncthreads();

    unsigned* dst = pb + (size_t)blk * WMAX;
    for (int i = threadIdx.x; i < W; i += 1024) dst[i] = lds[i];
}

// ---------------- K4: per-slice exclusive byte-bases + totals ----------------
__global__ __launch_bounds__(256) void k_combine(
    unsigned* __restrict__ pb, int* __restrict__ cnt, int n)
{
    const int W = (n + 3) >> 2;
    int t = blockIdx.x * 256 + threadIdx.x;
    if (t >= 2 * W) return;
    const int m = t / W, w = t % W;

    unsigned run = 0;
    unsigned* base = pb + ((size_t)m * NSL) * WMAX + w;
    for (int s = 0; s < NSL; ++s) {
        unsigned v = base[(size_t)s * WMAX];
        base[(size_t)s * WMAX] = run;   // exclusive byte-base of slice s
        run += v;                       // packed adds; bytes <= ~50, no carry
    }
    int bin = 4 * w;
    if (bin + 3 < n) {
        int4 c = make_int4(run & 0xFF, (run >> 8) & 0xFF,
                           (run >> 16) & 0xFF, (run >> 24) & 0xFF);
        *(int4*)&cnt[m * n + bin] = c;
    } else {
        for (int j = 0; j < 4 && bin + j < n; ++j)
            cnt[m * n + bin + j] = (run >> (8 * j)) & 0xFF;
    }
}

// ---------------- K5: exclusive scan over 2N counts (2-level) ----------------
__global__ __launch_bounds__(256) void k_scan1(
    const int* __restrict__ cnt, int* __restrict__ excl,
    int* __restrict__ bsum, int n2)
{
    __shared__ int sh[256];
    int t = threadIdx.x;
    int base = blockIdx.x * 1024 + t * 4;
    int v0 = (base + 0 < n2) ? cnt[base + 0] : 0;
    int v1 = (base + 1 < n2) ? cnt[base + 1] : 0;
    int v2 = (base + 2 < n2) ? cnt[base + 2] : 0;
    int v3 = (base + 3 < n2) ? cnt[base + 3] : 0;
    int s1 = v0 + v1, s2 = s1 + v2, s3 = s2 + v3;
    sh[t] = s3;
    __syncthreads();
    for (int off = 1; off < 256; off <<= 1) {
        int a = (t >= off) ? sh[t - off] : 0;
        __syncthreads();
        sh[t] += a;
        __syncthreads();
    }
    int eb = sh[t] - s3;
    if (t == 255) bsum[blockIdx.x] = sh[255];
    if (base + 0 < n2) excl[base + 0] = eb;
    if (base + 1 < n2) excl[base + 1] = eb + v0;
    if (base + 2 < n2) excl[base + 2] = eb + s1;
    if (base + 3 < n2) excl[base + 3] = eb + s2;
}

__global__ __launch_bounds__(256) void k_scan2(int* __restrict__ bsum, int nb)
{
    __shared__ int sh[256];
    int t = threadIdx.x;
    int v = (t < nb) ? bsum[t] : 0;
    sh[t] = v;
    __syncthreads();
    for (int off = 1; off < 256; off <<= 1) {
        int a = (t >= off) ? sh[t - off] : 0;
        __syncthreads();
        sh[t] += a;
        __syncthreads();
    }
    if (t < nb) bsum[t] = sh[t] - v;
}

__global__ __launch_bounds__(256) void k_scan3(
    int* __restrict__ rp, const int* __restrict__ bsum, int n2, int etot)
{
    int i = blockIdx.x * 256 + threadIdx.x;
    if (i < n2) rp[i] += bsum[i >> 10];
    if (i == 0) rp[n2] = etot;
}

// ---------------- K6: CSR fill via LDS re-rank (no global atomics) ----------------
__global__ __launch_bounds__(1024) void k_fill(
    const int* __restrict__ ei1, const int* __restrict__ ei2,
    const unsigned* __restrict__ pb, const int* __restrict__ rp,
    int* __restrict__ srcs, int n, int e)
{
    __shared__ unsigned lds[WMAX];
    const int blk = blockIdx.x;
    const int s   = blk % NSL;
    const int m   = blk / NSL;
    const int* ei = m ? ei2 : ei1;
    const int W   = (n + 3) >> 2;

    for (int i = threadIdx.x; i < W; i += 1024) lds[i] = 0;
    __syncthreads();

    const unsigned* sb = pb + (size_t)blk * WMAX;
    const int sl = (e + NSL - 1) / NSL;
    const int j0 = s * sl, j1 = min(j0 + sl, e);
    for (int j = j0 + threadIdx.x; j < j1; j += 1024) {
        int d  = ei[j];
        int sv = ei[e + j];
        int sh = (d & 3) * 8;
        unsigned old = atomicAdd(&lds[d >> 2], 1u << sh);
        int rank = (old >> sh) & 0xFF;
        int bse  = (sb[d >> 2] >> sh) & 0xFF;
        srcs[rp[m * n + d] + bse + rank] = sv;
    }
}

// ---- K7: fused gather — 4 edges/wave x 16 lanes x dwordx4, pk_fma ----
__global__ __launch_bounds__(256) void k_gather(
    const unsigned* __restrict__ h2,
    const float* __restrict__ exal0, const float* __restrict__ exal1,
    const float* __restrict__ betab,
    const int* __restrict__ rp, const int* __restrict__ srcs,
    float* __restrict__ out, int n)
{
    int wid  = blockIdx.x * 4 + (threadIdx.x >> 6);
    if (wid >= n) return;
    const int lane = threadIdx.x & 63;
    const int g    = lane >> 4;     // edge sub-slot 0..3
    const int q    = lane & 15;     // 16B feature chunk 0..15

    float b0 = betab[wid * 3 + 0];
    float b1 = betab[wid * 3 + 1];
    float b2 = betab[wid * 3 + 2];

    f32x2 acc[4];
#pragma unroll
    for (int c = 0; c < 4; ++c) acc[c] = (f32x2){0.f, 0.f};

#pragma unroll
    for (int m = 0; m < 2; ++m) {
        const int s0 = rp[m * n + wid];
        const int s1 = rp[m * n + wid + 1];
        const float* exal = m ? exal1 : exal0;
        const float bm = m ? b1 : b0;

        float sum = 0.0f;
        f32x2 ap[4];
#pragma unroll
        for (int c = 0; c < 4; ++c) ap[c] = (f32x2){0.f, 0.f};

        for (int base = s0; base < s1; base += 64) {
            const int cnt = min(64, s1 - base);

            int   src = 0;
            float ex  = 0.0f;
            if (lane < cnt) {
                src = srcs[base + lane];
                ex  = exal[src];          // dst-side softmax factor cancels
            }
            {
                float t = ex;
#pragma unroll
                for (int o = 32; o > 0; o >>= 1) t += __shfl_xor(t, o);
                sum += t;
            }

            int j = 0;
            // 2 quads (8 edges) per iteration: 2 dwordx4 loads in flight
            for (; j + 8 <= cnt; j += 8) {
                int   sA = __shfl(src, j + g);
                int   sB = __shfl(src, j + 4 + g);
                float wA = __shfl(ex,  j + g);
                float wB = __shfl(ex,  j + 4 + g);
                const uint4 uA = *(const uint4*)(h2 + (size_t)sA * 64 + q * 4);
                const uint4 uB = *(const uint4*)(h2 + (size_t)sB * 64 + q * 4);
                f32x2 wa = {wA, wA}, wb = {wB, wB};
                ap[0] = __builtin_elementwise_fma(wa, (f32x2){bflo(uA.x), bfhi(uA.x)}, ap[0]);
                ap[1] = __builtin_elementwise_fma(wa, (f32x2){bflo(uA.y), bfhi(uA.y)}, ap[1]);
                ap[2] = __builtin_elementwise_fma(wa, (f32x2){bflo(uA.z), bfhi(uA.z)}, ap[2]);
                ap[3] = __builtin_elementwise_fma(wa, (f32x2){bflo(uA.w), bfhi(uA.w)}, ap[3]);
                ap[0] = __builtin_elementwise_fma(wb, (f32x2){bflo(uB.x), bfhi(uB.x)}, ap[0]);
                ap[1] = __builtin_elementwise_fma(wb, (f32x2){bflo(uB.y), bfhi(uB.y)}, ap[1]);
                ap[2] = __builtin_elementwise_fma(wb, (f32x2){bflo(uB.z), bfhi(uB.z)}, ap[2]);
                ap[3] = __builtin_elementwise_fma(wb, (f32x2){bflo(uB.w), bfhi(uB.w)}, ap[3]);
            }
            for (; j + 4 <= cnt; j += 4) {
                int   sA = __shfl(src, j + g);
                float wA = __shfl(ex,  j + g);
                const uint4 uA = *(const uint4*)(h2 + (size_t)sA * 64 + q * 4);
                f32x2 wa = {wA, wA};
                ap[0] = __builtin_elementwise_fma(wa, (f32x2){bflo(uA.x), bfhi(uA.x)}, ap[0]);
                ap[1] = __builtin_elementwise_fma(wa, (f32x2){bflo(uA.y), bfhi(uA.y)}, ap[1]);
                ap[2] = __builtin_elementwise_fma(wa, (f32x2){bflo(uA.z), bfhi(uA.z)}, ap[2]);
                ap[3] = __builtin_elementwise_fma(wa, (f32x2){bflo(uA.w), bfhi(uA.w)}, ap[3]);
            }
            {   // tail 1..3 edges: groups g < rem participate
                const int rem = cnt - j;
                int   sA = __shfl(src, j + (g < rem ? g : 0));
                float wA = __shfl(ex,  j + (g < rem ? g : 0));
                if (g < rem) {
                    const uint4 uA = *(const uint4*)(h2 + (size_t)sA * 64 + q * 4);
                    f32x2 wa = {wA, wA};
                    ap[0] = __builtin_elementwise_fma(wa, (f32x2){bflo(uA.x), bfhi(uA.x)}, ap[0]);
                    ap[1] = __builtin_elementwise_fma(wa, (f32x2){bflo(uA.y), bfhi(uA.y)}, ap[1]);
                    ap[2] = __builtin_elementwise_fma(wa, (f32x2){bflo(uA.z), bfhi(uA.z)}, ap[2]);
                    ap[3] = __builtin_elementwise_fma(wa, (f32x2){bflo(uA.w), bfhi(uA.w)}, ap[3]);
                }
            }
        }

        const float sc = bm / (sum + 1e-16f);
        f32x2 s2 = {sc, sc};
#pragma unroll
        for (int c = 0; c < 4; ++c)
            acc[c] = __builtin_elementwise_fma(s2, ap[c], acc[c]);
    }

    // reduce across the 4 edge-groups (lanes differing in bits 4,5)
#pragma unroll
    for (int o = 16; o <= 32; o <<= 1) {
#pragma unroll
        for (int c = 0; c < 4; ++c) {
            acc[c].x += __shfl_xor(acc[c].x, o);
            acc[c].y += __shfl_xor(acc[c].y, o);
        }
    }

    if (g == 0) {
        // self channel + relu + store (lane q owns features [q*8, q*8+8))
        const uint4 su = *(const uint4*)(h2 + (size_t)wid * 64 + q * 4);
        float4 o0, o1;
        o0.x = fmaxf(fmaf(b2, bflo(su.x), acc[0].x), 0.0f);
        o0.y = fmaxf(fmaf(b2, bfhi(su.x), acc[0].y), 0.0f);
        o0.z = fmaxf(fmaf(b2, bflo(su.y), acc[1].x), 0.0f);
        o0.w = fmaxf(fmaf(b2, bfhi(su.y), acc[1].y), 0.0f);
        o1.x = fmaxf(fmaf(b2, bflo(su.z), acc[2].x), 0.0f);
        o1.y = fmaxf(fmaf(b2, bfhi(su.z), acc[2].y), 0.0f);
        o1.z = fmaxf(fmaf(b2, bflo(su.w), acc[3].x), 0.0f);
        o1.w = fmaxf(fmaf(b2, bfhi(su.w), acc[3].y), 0.0f);
        *(float4*)(out + (size_t)wid * DIM + q * 8)     = o0;
        *(float4*)(out + (size_t)wid * DIM + q * 8 + 4) = o1;
    }
}

extern "C" void kernel_launch(void* const* d_in, const int* in_sizes, int n_in,
                              void* d_out, int out_size, void* d_ws, size_t ws_size,
                              hipStream_t stream)
{
    const float* x     = (const float*)d_in[0];
    const int*   ei1   = (const int*)d_in[1];
    const int*   ei2   = (const int*)d_in[2];
    const float* W_lin = (const float*)d_in[3];
    const float* b_lin = (const float*)d_in[4];
    const float* W_cv  = (const float*)d_in[5];
    const float* b_cv  = (const float*)d_in[6];
    const float* alw   = (const float*)d_in[7];
    const float* alb   = (const float*)d_in[8];
    const float* alpha = (const float*)d_in[11];

    const int N  = in_sizes[0] / DIM;
    const int E  = in_sizes[1] / 2;
    const int N2 = 2 * N;
    const int W  = (N + 3) >> 2;

    float* out = (float*)d_out;

    // workspace layout (4-byte units)
    unsigned* h2    = (unsigned*)d_ws;                  // N*64
    float*    exal0 = (float*)(h2 + (size_t)N * 64);    // N
    float*    exal1 = exal0 + N;                        // N
    float*    betab = exal1 + N;                        // 3N
    int*      rp    = (int*)(betab + (size_t)3 * N);    // 2N+2
    int*      cnt   = rp + (N2 + 2);                    // 2N
    int*      bsum  = cnt + N2;                         // 256
    unsigned* pb    = (unsigned*)(bsum + 256);          // 2*NSL*WMAX
    int*      srcs  = (int*)(pb + (size_t)2 * NSL * WMAX); // 2E

    const int nb = (N2 + 1023) / 1024;

    k_gemm_h<<<(N + 63) / 64, 256, 0, stream>>>(x, W_lin, b_lin, W_cv, b_cv,
                                                alw, alb, alpha,
                                                (unsigned short*)h2,
                                                exal0, exal1, betab, N);

    k_hist<<<2 * NSL, 1024, 0, stream>>>(ei1, ei2, pb, N, E);

    k_combine<<<(2 * W + 255) / 256, 256, 0, stream>>>(pb, cnt, N);

    k_scan1<<<nb, 256, 0, stream>>>(cnt, rp, bsum, N2);
    k_scan2<<<1, 256, 0, stream>>>(bsum, nb);
    k_scan3<<<(N2 + 255) / 256, 256, 0, stream>>>(rp, bsum, N2, 2 * E);

    k_fill<<<2 * NSL, 1024, 0, stream>>>(ei1, ei2, pb, rp, srcs, N, E);

    k_gather<<<(N + 3) / 4, 256, 0, stream>>>(h2, exal0, exal1, betab,
                                              rp, srcs, out, N);
}

// Round 12
// 257.673 us; speedup vs baseline: 1.0697x; 1.0697x over previous
//
#include <hip/hip_runtime.h>

#define DIM 128
#define NSL 128            // edge slices per metapath (256 blocks total, 1/CU)
#define WMAX 25000         // N/4 packed-byte words (100 KB LDS, full N)

typedef __attribute__((ext_vector_type(8))) short bf16x8;
typedef __attribute__((ext_vector_type(4))) float f32x4;

__device__ __forceinline__ unsigned bfbits(float f) {
    unsigned u = __float_as_uint(f);
    return (u + 0x7FFFu + ((u >> 16) & 1u)) >> 16;   // RNE bf16
}
__device__ __forceinline__ float bflo(unsigned u) { return __uint_as_float(u << 16); }
__device__ __forceinline__ float bfhi(unsigned u) { return __uint_as_float(u & 0xFFFF0000u); }

// ---- K1: h2(bf16) = x @ W_lin^T + b_lin via MFMA; fused al/beta epilogue ----
__global__ __launch_bounds__(256) void k_gemm_h(
    const float* __restrict__ x, const float* __restrict__ W,
    const float* __restrict__ b, const float* __restrict__ Wc,
    const float* __restrict__ bcv, const float* __restrict__ alw,
    const float* __restrict__ alb, const float* __restrict__ alpha,
    unsigned short* __restrict__ h2u, float* __restrict__ exal0,
    float* __restrict__ exal1, float* __restrict__ betab, int n)
{
    __shared__ short wlds[128 * 136];
    __shared__ short xlds[64 * 136];
    const int tid  = threadIdx.x;
    const int row0 = blockIdx.x * 64;

    {
        const int j = tid >> 1, half = tid & 1;
        const float4* W4 = (const float4*)W;
#pragma unroll
        for (int i = 0; i < 8; ++i) {
            float4 fa = W4[j * 32 + half * 16 + i * 2];
            float4 fb = W4[j * 32 + half * 16 + i * 2 + 1];
            uint4 p;
            p.x = bfbits(fa.x) | (bfbits(fa.y) << 16);
            p.y = bfbits(fa.z) | (bfbits(fa.w) << 16);
            p.z = bfbits(fb.x) | (bfbits(fb.y) << 16);
            p.w = bfbits(fb.z) | (bfbits(fb.w) << 16);
            *(uint4*)&wlds[j * 136 + half * 64 + i * 8] = p;
        }
    }
    {
        const int r = tid >> 2, q = tid & 3;
        const int row = min(row0 + r, n - 1);
        const float4* x4 = (const float4*)x;
#pragma unroll
        for (int i = 0; i < 4; ++i) {
            float4 fa = x4[(size_t)row * 32 + q * 8 + i * 2];
            float4 fb = x4[(size_t)row * 32 + q * 8 + i * 2 + 1];
            uint4 p;
            p.x = bfbits(fa.x) | (bfbits(fa.y) << 16);
            p.y = bfbits(fa.z) | (bfbits(fa.w) << 16);
            p.z = bfbits(fb.x) | (bfbits(fb.y) << 16);
            p.w = bfbits(fb.z) | (bfbits(fb.w) << 16);
            *(uint4*)&xlds[r * 136 + q * 32 + i * 8] = p;
        }
    }
    __syncthreads();

    const int wv = tid >> 6, lane = tid & 63;
    const int lr = lane & 15, lg = lane >> 4;

    f32x4 acc[8];
#pragma unroll
    for (int c = 0; c < 8; ++c) acc[c] = (f32x4){0.f, 0.f, 0.f, 0.f};

#pragma unroll
    for (int ks = 0; ks < 4; ++ks) {
        bf16x8 a = *(const bf16x8*)&xlds[(wv * 16 + lr) * 136 + ks * 32 + lg * 8];
#pragma unroll
        for (int c = 0; c < 8; ++c) {
            bf16x8 bb = *(const bf16x8*)&wlds[(c * 16 + lr) * 136 + ks * 32 + lg * 8];
            acc[c] = __builtin_amdgcn_mfma_f32_16x16x32_bf16(a, bb, acc[c], 0, 0, 0);
        }
    }

    // epilogue: C/D layout col=lane&15, row=(lane>>4)*4+reg  [m89-verified]
    const int rl0 = wv * 16 + lg * 4;      // local row base
    float as0[4] = {0.f,0.f,0.f,0.f}, as1[4] = {0.f,0.f,0.f,0.f};
#pragma unroll
    for (int c = 0; c < 8; ++c) {
        const int col = c * 16 + lr;
        const float bc = b[col];
        const float w0 = alw[col], w1 = alw[128 + col];
#pragma unroll
        for (int r = 0; r < 4; ++r) {
            const float hv = acc[c][r] + bc;
            const int row = row0 + rl0 + r;
            if (row < n)
                h2u[(size_t)row * DIM + col] = (unsigned short)bfbits(hv);
            as0[r] = fmaf(hv, w0, as0[r]);
            as1[r] = fmaf(hv, w1, as1[r]);
        }
    }
    float xs0[4] = {0.f,0.f,0.f,0.f}, xs1[4] = {0.f,0.f,0.f,0.f},
          xs2[4] = {0.f,0.f,0.f,0.f};
#pragma unroll
    for (int i = 0; i < 8; ++i) {
        const int col = lr + i * 16;
        const float wc0 = Wc[col], wc1 = Wc[128 + col], wc2 = Wc[256 + col];
#pragma unroll
        for (int r = 0; r < 4; ++r) {
            const float xv = bflo((unsigned)(unsigned short)xlds[(rl0 + r) * 136 + col]);
            xs0[r] = fmaf(xv, wc0, xs0[r]);
            xs1[r] = fmaf(xv, wc1, xs1[r]);
            xs2[r] = fmaf(xv, wc2, xs2[r]);
        }
    }
#pragma unroll
    for (int o = 1; o <= 8; o <<= 1) {
#pragma unroll
        for (int r = 0; r < 4; ++r) {
            as0[r] += __shfl_xor(as0[r], o);
            as1[r] += __shfl_xor(as1[r], o);
            xs0[r] += __shfl_xor(xs0[r], o);
            xs1[r] += __shfl_xor(xs1[r], o);
            xs2[r] += __shfl_xor(xs2[r], o);
        }
    }
    if (lr == 0) {
        const float a0 = alpha[0], a1 = alpha[1];
        const float ab0 = alb[0], ab1 = alb[1];
        const float b0 = bcv[0], b1 = bcv[1], b2 = bcv[2];
#pragma unroll
        for (int r = 0; r < 4; ++r) {
            const int row = row0 + rl0 + r;
            if (row < n) {
                exal0[row] = __expf(a0 * (as0[r] + ab0));
                exal1[row] = __expf(a1 * (as1[r] + ab1));
                float c0 = xs0[r] + b0, c1 = xs1[r] + b1, c2 = xs2[r] + b2;
                float mx = fmaxf(c0, fmaxf(c1, c2));
                float e0 = __expf(c0 - mx), e1 = __expf(c1 - mx),
                      e2 = __expf(c2 - mx);
                float s = e0 + e1 + e2;
                betab[row * 3 + 0] = e0 / s;
                betab[row * 3 + 1] = e1 / s;
                betab[row * 3 + 2] = e2 / s;
            }
        }
    }
}

// ---- K3: per-(metapath,slice) full-N LDS histogram + per-edge rank byte ----
__global__ __launch_bounds__(1024) void k_hist(
    const int* __restrict__ ei1, const int* __restrict__ ei2,
    unsigned* __restrict__ pb, unsigned char* __restrict__ ph, int n, int e)
{
    __shared__ unsigned lds[WMAX];
    const int blk = blockIdx.x;
    const int s   = blk % NSL;
    const int m   = blk / NSL;
    const int* ei = m ? ei2 : ei1;
    const int W   = (n + 3) >> 2;

    for (int i = threadIdx.x; i < W; i += 1024) lds[i] = 0;
    __syncthreads();

    const int sl = (e + NSL - 1) / NSL;
    const int j0 = s * sl, j1 = min(j0 + sl, e);
    for (int j = j0 + threadIdx.x; j < j1; j += 1024) {
        int d  = ei[j];
        int sh = (d & 3) * 8;
        unsigned old = atomicAdd(&lds[d >> 2], 1u << sh);
        ph[(size_t)m * e + j] = (unsigned char)((old >> sh) & 0xFF);
    }
    __syncthreads();

    unsigned* dst = pb + (size_t)blk * WMAX;
    for (int i = threadIdx.x; i < W; i += 1024) dst[i] = lds[i];
}

// ---------------- K4: per-slice exclusive byte-bases + totals ----------------
__global__ __launch_bounds__(256) void k_combine(
    unsigned* __restrict__ pb, int* __restrict__ cnt, int n)
{
    const int W = (n + 3) >> 2;
    int t = blockIdx.x * 256 + threadIdx.x;
    if (t >= 2 * W) return;
    const int m = t / W, w = t % W;

    unsigned run = 0;
    unsigned* base = pb + ((size_t)m * NSL) * WMAX + w;
    for (int s = 0; s < NSL; ++s) {
        unsigned v = base[(size_t)s * WMAX];
        base[(size_t)s * WMAX] = run;   // exclusive byte-base of slice s
        run += v;                       // packed adds; bytes <= ~50, no carry
    }
    int bin = 4 * w;
    if (bin + 3 < n) {
        int4 c = make_int4(run & 0xFF, (run >> 8) & 0xFF,
                           (run >> 16) & 0xFF, (run >> 24) & 0xFF);
        *(int4*)&cnt[m * n + bin] = c;
    } else {
        for (int j = 0; j < 4 && bin + j < n; ++j)
            cnt[m * n + bin + j] = (run >> (8 * j)) & 0xFF;
    }
}

// ---------------- K5: exclusive scan over 2N counts (2-level) ----------------
__global__ __launch_bounds__(256) void k_scan1(
    const int* __restrict__ cnt, int* __restrict__ excl,
    int* __restrict__ bsum, int n2)
{
    __shared__ int sh[256];
    int t = threadIdx.x;
    int base = blockIdx.x * 1024 + t * 4;
    int v0 = (base + 0 < n2) ? cnt[base + 0] : 0;
    int v1 = (base + 1 < n2) ? cnt[base + 1] : 0;
    int v2 = (base + 2 < n2) ? cnt[base + 2] : 0;
    int v3 = (base + 3 < n2) ? cnt[base + 3] : 0;
    int s1 = v0 + v1, s2 = s1 + v2, s3 = s2 + v3;
    sh[t] = s3;
    __syncthreads();
    for (int off = 1; off < 256; off <<= 1) {
        int a = (t >= off) ? sh[t - off] : 0;
        __syncthreads();
        sh[t] += a;
        __syncthreads();
    }
    int eb = sh[t] - s3;
    if (t == 255) bsum[blockIdx.x] = sh[255];
    if (base + 0 < n2) excl[base + 0] = eb;
    if (base + 1 < n2) excl[base + 1] = eb + v0;
    if (base + 2 < n2) excl[base + 2] = eb + s1;
    if (base + 3 < n2) excl[base + 3] = eb + s2;
}

__global__ __launch_bounds__(256) void k_scan2(int* __restrict__ bsum, int nb)
{
    __shared__ int sh[256];
    int t = threadIdx.x;
    int v = (t < nb) ? bsum[t] : 0;
    sh[t] = v;
    __syncthreads();
    for (int off = 1; off < 256; off <<= 1) {
        int a = (t >= off) ? sh[t - off] : 0;
        __syncthreads();
        sh[t] += a;
        __syncthreads();
    }
    if (t < nb) bsum[t] = sh[t] - v;
}

__global__ __launch_bounds__(256) void k_scan3(
    int* __restrict__ rp, const int* __restrict__ bsum, int n2, int etot)
{
    int i = blockIdx.x * 256 + threadIdx.x;
    if (i < n2) rp[i] += bsum[i >> 10];
    if (i == 0) rp[n2] = etot;
}

// ---- K6: CSR fill — elementwise, no LDS, no atomics (uses hist ranks) ----
__global__ __launch_bounds__(256) void k_fill(
    const int* __restrict__ ei1, const int* __restrict__ ei2,
    const unsigned char* __restrict__ ph, const unsigned* __restrict__ pb,
    const int* __restrict__ rp, int* __restrict__ srcs,
    int sl, int n, int e)
{
    int t = blockIdx.x * 256 + threadIdx.x;
    if (t >= 2 * e) return;
    const int m = (t >= e);
    const int j = t - m * e;
    const int* ei = m ? ei2 : ei1;
    const int d  = ei[j];
    const int sv = ei[e + j];
    const int s  = j / sl;
    const int sh = (d & 3) * 8;
    const int bse  = (pb[((size_t)(m * NSL + s)) * WMAX + (d >> 2)] >> sh) & 0xFF;
    const int rank = ph[t];
    srcs[rp[m * n + d] + bse + rank] = sv;
}

// ---------------- K7: fused gather (bf16, 8-deep, exal) + self + relu ------
__global__ __launch_bounds__(256) void k_gather(
    const unsigned* __restrict__ h2,
    const float* __restrict__ exal0, const float* __restrict__ exal1,
    const float* __restrict__ betab,
    const int* __restrict__ rp, const int* __restrict__ srcs,
    float* __restrict__ out, int n)
{
    int wid  = blockIdx.x * 4 + (threadIdx.x >> 6);
    if (wid >= n) return;
    int lane = threadIdx.x & 63;

    float b0 = betab[wid * 3 + 0];
    float b1 = betab[wid * 3 + 1];
    float b2 = betab[wid * 3 + 2];

    float2 acc;
    {
        unsigned hu = h2[(size_t)wid * 64 + lane];
        acc.x = b2 * bflo(hu);
        acc.y = b2 * bfhi(hu);
    }

#pragma unroll
    for (int m = 0; m < 2; ++m) {
        const int s0 = rp[m * n + wid];
        const int s1 = rp[m * n + wid + 1];
        const float* exal = m ? exal1 : exal0;
        const float bm = m ? b1 : b0;

        float sum = 0.0f;
        float2 a = {0.0f, 0.0f};

        for (int base = s0; base < s1; base += 64) {
            const int cnt = min(64, s1 - base);

            int   src = 0;
            float ex  = 0.0f;
            if (lane < cnt) {
                src = srcs[base + lane];
                ex  = exal[src];          // dst-side softmax factor cancels
            }
            {
                float t = ex;
#pragma unroll
                for (int o = 32; o > 0; o >>= 1) t += __shfl_xor(t, o);
                sum += t;
            }

            const unsigned exu = __float_as_uint(ex);
            int j = 0;
            for (; j + 8 <= cnt; j += 8) {
                unsigned u[8];
                float    w[8];
#pragma unroll
                for (int q = 0; q < 8; ++q) {
                    int s = __builtin_amdgcn_readlane(src, j + q);
                    w[q]  = __uint_as_float(__builtin_amdgcn_readlane(exu, j + q));
                    u[q]  = h2[(size_t)s * 64 + lane];
                }
#pragma unroll
                for (int q = 0; q < 8; ++q) {
                    a.x = fmaf(w[q], bflo(u[q]), a.x);
                    a.y = fmaf(w[q], bfhi(u[q]), a.y);
                }
            }
            for (; j + 2 <= cnt; j += 2) {
                int   sA = __builtin_amdgcn_readlane(src, j + 0);
                int   sB = __builtin_amdgcn_readlane(src, j + 1);
                float wA = __uint_as_float(__builtin_amdgcn_readlane(exu, j + 0));
                float wB = __uint_as_float(__builtin_amdgcn_readlane(exu, j + 1));
                unsigned uA = h2[(size_t)sA * 64 + lane];
                unsigned uB = h2[(size_t)sB * 64 + lane];
                a.x = fmaf(wA, bflo(uA), a.x); a.y = fmaf(wA, bfhi(uA), a.y);
                a.x = fmaf(wB, bflo(uB), a.x); a.y = fmaf(wB, bfhi(uB), a.y);
            }
            if (j < cnt) {
                int   sA = __builtin_amdgcn_readlane(src, j);
                float wA = __uint_as_float(__builtin_amdgcn_readlane(exu, j));
                unsigned uA = h2[(size_t)sA * 64 + lane];
                a.x = fmaf(wA, bflo(uA), a.x);
                a.y = fmaf(wA, bfhi(uA), a.y);
            }
        }

        float sc = bm / (sum + 1e-16f);
        acc.x = fmaf(sc, a.x, acc.x);
        acc.y = fmaf(sc, a.y, acc.y);
    }

    float2 o;
    o.x = fmaxf(acc.x, 0.0f);
    o.y = fmaxf(acc.y, 0.0f);
    *(float2*)(out + (size_t)wid * DIM + lane * 2) = o;
}

extern "C" void kernel_launch(void* const* d_in, const int* in_sizes, int n_in,
                              void* d_out, int out_size, void* d_ws, size_t ws_size,
                              hipStream_t stream)
{
    const float* x     = (const float*)d_in[0];
    const int*   ei1   = (const int*)d_in[1];
    const int*   ei2   = (const int*)d_in[2];
    const float* W_lin = (const float*)d_in[3];
    const float* b_lin = (const float*)d_in[4];
    const float* W_cv  = (const float*)d_in[5];
    const float* b_cv  = (const float*)d_in[6];
    const float* alw   = (const float*)d_in[7];
    const float* alb   = (const float*)d_in[8];
    const float* alpha = (const float*)d_in[11];

    const int N  = in_sizes[0] / DIM;
    const int E  = in_sizes[1] / 2;
    const int N2 = 2 * N;
    const int W  = (N + 3) >> 2;
    const int SL = (E + NSL - 1) / NSL;

    float* out = (float*)d_out;

    // workspace layout (4-byte units)
    unsigned* h2    = (unsigned*)d_ws;                  // N*64
    float*    exal0 = (float*)(h2 + (size_t)N * 64);    // N
    float*    exal1 = exal0 + N;                        // N
    float*    betab = exal1 + N;                        // 3N
    int*      rp    = (int*)(betab + (size_t)3 * N);    // 2N+2
    int*      cnt   = rp + (N2 + 2);                    // 2N
    int*      bsum  = cnt + N2;                         // 256
    unsigned* pb    = (unsigned*)(bsum + 256);          // 2*NSL*WMAX
    unsigned char* ph = (unsigned char*)(pb + (size_t)2 * NSL * WMAX); // 2E bytes
    int*      srcs  = (int*)(ph + (size_t)2 * E);       // 2E

    const int nb = (N2 + 1023) / 1024;

    k_gemm_h<<<(N + 63) / 64, 256, 0, stream>>>(x, W_lin, b_lin, W_cv, b_cv,
                                                alw, alb, alpha,
                                                (unsigned short*)h2,
                                                exal0, exal1, betab, N);

    k_hist<<<2 * NSL, 1024, 0, stream>>>(ei1, ei2, pb, ph, N, E);

    k_combine<<<(2 * W + 255) / 256, 256, 0, stream>>>(pb, cnt, N);

    k_scan1<<<nb, 256, 0, stream>>>(cnt, rp, bsum, N2);
    k_scan2<<<1, 256, 0, stream>>>(bsum, nb);
    k_scan3<<<(N2 + 255) / 256, 256, 0, stream>>>(rp, bsum, N2, 2 * E);

    k_fill<<<(2 * E + 255) / 256, 256, 0, stream>>>(ei1, ei2, ph, pb, rp, srcs,
                                                    SL, N, E);

    k_gather<<<(N + 3) / 4, 256, 0, stream>>>(h2, exal0, exal1, betab,
                                              rp, srcs, out, N);
}